// Round 14
// baseline (475.476 us; speedup 1.0000x reference)
//
#include <hip/hip_runtime.h>
#include <hip/hip_bf16.h>
#include <hip/hip_fp16.h>
#include <math.h>

#define DF 128          // feature dim
#define NLAYERS 5

typedef __attribute__((ext_vector_type(8))) _Float16 f16x8;
typedef __attribute__((ext_vector_type(4))) _Float16 f16x4;
typedef __attribute__((ext_vector_type(4))) float f32x4;

// packed fp16 max on raw bits (ROCm 7.2 lacks a viable fp16 __hmax2 overload)
__device__ inline unsigned pkmax(unsigned a, unsigned b) {
    unsigned d;
    asm("v_pk_max_f16 %0, %1, %2" : "=v"(d) : "v"(a), "v"(b));
    return d;
}
__device__ inline float h2f(unsigned short u) {
    __half_raw r; r.x = u;
    return __half2float(__half(r));
}
__device__ inline float silu(float v) {
    return v * (1.0f / (1.0f + __expf(-v)));
}

// split 8 consecutive fp32 into fp16 hi + fp16 lo (hi+lo ~ 2^-22 accurate)
__device__ inline void split8f(const float* p, f16x8& hi, f16x8& lo) {
    float4 v0 = *reinterpret_cast<const float4*>(p);
    float4 v1 = *reinterpret_cast<const float4*>(p + 4);
    float f[8] = {v0.x, v0.y, v0.z, v0.w, v1.x, v1.y, v1.z, v1.w};
#pragma unroll
    for (int j = 0; j < 8; ++j) {
        _Float16 a = (_Float16)f[j];
        hi[j] = a;
        lo[j] = (_Float16)(f[j] - (float)a);
    }
}

// ---------------- zero cnt ----------------

__global__ __launch_bounds__(256) void zero_kernel(int* __restrict__ p, int n) {
    int i = blockIdx.x * 256 + threadIdx.x;
    if (i < n) p[i] = 0;
}

// ---------------- prep: histogram+rank (blocks [0,nbE)) | W->fp16 pair (rest) --

__global__ __launch_bounds__(256) void prep_kernel(const int* __restrict__ dst,
        int* __restrict__ cnt, unsigned short* __restrict__ rank, int E, int nbE,
        const float* __restrict__ Ws, _Float16* __restrict__ whf,
        _Float16* __restrict__ wlf, int wt4) {
    int b = blockIdx.x;
    int t = threadIdx.x;
    if (b < nbE) {
        int i = b * 256 + t;
        if (i < E) rank[i] = (unsigned short)atomicAdd(&cnt[dst[i]], 1);
    } else {
        int i = (b - nbE) * 256 + t;
        if (i < wt4) {
            float4 v = reinterpret_cast<const float4*>(Ws)[i];
            float f[4] = {v.x, v.y, v.z, v.w};
            f16x4 h, l;
#pragma unroll
            for (int j = 0; j < 4; ++j) {
                _Float16 a = (_Float16)f[j];
                h[j] = a;
                l[j] = (_Float16)(f[j] - (float)a);
            }
            reinterpret_cast<f16x4*>(whf)[i] = h;
            reinterpret_cast<f16x4*>(wlf)[i] = l;
        }
    }
}

// ---------------- CSR scan chain ----------------

__global__ __launch_bounds__(256) void partial_sum_kernel(const int* __restrict__ cnt,
        int* __restrict__ bsum, int n) {
    __shared__ int red[256];
    int t = threadIdx.x;
    int i = blockIdx.x * 256 + t;
    red[t] = (i < n) ? cnt[i] : 0;
    __syncthreads();
    for (int d = 128; d > 0; d >>= 1) {
        if (t < d) red[t] += red[t + d];
        __syncthreads();
    }
    if (t == 0) bsum[blockIdx.x] = red[0];
}

__global__ __launch_bounds__(256) void scan_scatter_kernel(const int* __restrict__ cnt,
        const int* __restrict__ bsum, int* __restrict__ off, int n, int E, int nb) {
    __shared__ int sb[256];
    __shared__ int s[256];
    int t = threadIdx.x;
    int bv = (t < nb) ? bsum[t] : 0;
    sb[t] = bv;
    __syncthreads();
    for (int d = 1; d < 256; d <<= 1) {
        int u = (t >= d) ? sb[t - d] : 0;
        __syncthreads();
        sb[t] += u;
        __syncthreads();
    }
    int base = (blockIdx.x > 0) ? sb[blockIdx.x - 1] : 0;
    int i = blockIdx.x * 256 + t;
    int v = (i < n) ? cnt[i] : 0;
    s[t] = v;
    __syncthreads();
    for (int d = 1; d < 256; d <<= 1) {
        int u = (t >= d) ? s[t - d] : 0;
        __syncthreads();
        s[t] += u;
        __syncthreads();
    }
    int excl = s[t] - v + base;
    if (i < n) off[i] = excl;
    if (blockIdx.x == 0 && t == 0) off[n] = E;
}

// ---------------- fused: CSR fill (ushort) | layer-0 GEMM f16 ----------------

__global__ __launch_bounds__(256, 3) void fill_gemm0_kernel(
        const int* __restrict__ src, const int* __restrict__ dst,
        const int* __restrict__ off, const unsigned short* __restrict__ rank,
        unsigned short* __restrict__ csr, int E, int nbE,
        const float* __restrict__ x,
        const _Float16* __restrict__ whf, const _Float16* __restrict__ wlf,
        const float* __restrict__ bias, __half* __restrict__ h, int n) {
    if (blockIdx.x < nbE) {
        int i = blockIdx.x * 256 + threadIdx.x;
        if (i < E) csr[off[dst[i]] + (int)rank[i]] = (unsigned short)src[i];
        return;
    }
    int bid = blockIdx.x - nbE;

    int wave = threadIdx.x >> 6;
    int lane = threadIdx.x & 63;
    int wm = wave >> 1;
    int wn = wave & 1;
    int m0 = bid * 64 + wm * 32;
    int n0 = wn * 64;
    int lr = lane & 15;
    int lk = lane >> 4;

    f32x4 acc[2][4];
#pragma unroll
    for (int mt = 0; mt < 2; ++mt)
#pragma unroll
        for (int nt = 0; nt < 4; ++nt) {
            float bv = bias[n0 + nt * 16 + lr];
            acc[mt][nt] = (f32x4){bv, bv, bv, bv};
        }

    int rowA0 = min(m0 + lr, n - 1);
    int rowA1 = min(m0 + 16 + lr, n - 1);

#pragma unroll
    for (int ks = 0; ks < 4; ++ks) {
        int ko = ks * 32 + lk * 8;
        f16x8 a0h, a0l, a1h, a1l;
        split8f(x + (size_t)rowA0 * DF + ko, a0h, a0l);
        split8f(x + (size_t)rowA1 * DF + ko, a1h, a1l);
#pragma unroll
        for (int nt = 0; nt < 4; ++nt) {
            int ncol = n0 + nt * 16 + lr;
            f16x8 wh = *(const f16x8*)(whf + ncol * DF + ko);
            f16x8 wl = *(const f16x8*)(wlf + ncol * DF + ko);
            acc[0][nt] = __builtin_amdgcn_mfma_f32_16x16x32_f16(a0h, wh, acc[0][nt], 0, 0, 0);
            acc[0][nt] = __builtin_amdgcn_mfma_f32_16x16x32_f16(a0l, wh, acc[0][nt], 0, 0, 0);
            acc[0][nt] = __builtin_amdgcn_mfma_f32_16x16x32_f16(a0h, wl, acc[0][nt], 0, 0, 0);
            acc[1][nt] = __builtin_amdgcn_mfma_f32_16x16x32_f16(a1h, wh, acc[1][nt], 0, 0, 0);
            acc[1][nt] = __builtin_amdgcn_mfma_f32_16x16x32_f16(a1l, wh, acc[1][nt], 0, 0, 0);
            acc[1][nt] = __builtin_amdgcn_mfma_f32_16x16x32_f16(a1h, wl, acc[1][nt], 0, 0, 0);
        }
    }

#pragma unroll
    for (int mt = 0; mt < 2; ++mt) {
        int rbase = m0 + mt * 16 + lk * 4;
#pragma unroll
        for (int j = 0; j < 4; ++j) {
            int r = rbase + j;
            if (r < n) {
#pragma unroll
                for (int nt = 0; nt < 4; ++nt)
                    h[(size_t)r * DF + n0 + nt * 16 + lr] = __float2half(acc[mt][nt][j]);
            }
        }
    }
}

// ---------------- GEMM layers 1-4: A = fp16 x (exact), B = fp16 W pair --------

__global__ __launch_bounds__(256, 3) void gemm_f16_kernel(
        const _Float16* __restrict__ xf,
        const _Float16* __restrict__ whf, const _Float16* __restrict__ wlf,
        const float* __restrict__ bias, __half* __restrict__ h, int n) {
    int wave = threadIdx.x >> 6;
    int lane = threadIdx.x & 63;
    int wm = wave >> 1;
    int wn = wave & 1;
    int m0 = blockIdx.x * 64 + wm * 32;
    int n0 = wn * 64;
    int lr = lane & 15;
    int lk = lane >> 4;

    f32x4 acc[2][4];
#pragma unroll
    for (int mt = 0; mt < 2; ++mt)
#pragma unroll
        for (int nt = 0; nt < 4; ++nt) {
            float bv = bias[n0 + nt * 16 + lr];
            acc[mt][nt] = (f32x4){bv, bv, bv, bv};
        }

    int rowA0 = min(m0 + lr, n - 1);
    int rowA1 = min(m0 + 16 + lr, n - 1);

#pragma unroll
    for (int ks = 0; ks < 4; ++ks) {
        int ko = ks * 32 + lk * 8;
        f16x8 a0 = *(const f16x8*)(xf + (size_t)rowA0 * DF + ko);
        f16x8 a1 = *(const f16x8*)(xf + (size_t)rowA1 * DF + ko);
#pragma unroll
        for (int nt = 0; nt < 4; ++nt) {
            int ncol = n0 + nt * 16 + lr;
            f16x8 wh = *(const f16x8*)(whf + ncol * DF + ko);
            f16x8 wl = *(const f16x8*)(wlf + ncol * DF + ko);
            acc[0][nt] = __builtin_amdgcn_mfma_f32_16x16x32_f16(a0, wh, acc[0][nt], 0, 0, 0);
            acc[0][nt] = __builtin_amdgcn_mfma_f32_16x16x32_f16(a0, wl, acc[0][nt], 0, 0, 0);
            acc[1][nt] = __builtin_amdgcn_mfma_f32_16x16x32_f16(a1, wh, acc[1][nt], 0, 0, 0);
            acc[1][nt] = __builtin_amdgcn_mfma_f32_16x16x32_f16(a1, wl, acc[1][nt], 0, 0, 0);
        }
    }

#pragma unroll
    for (int mt = 0; mt < 2; ++mt) {
        int rbase = m0 + mt * 16 + lk * 4;
#pragma unroll
        for (int j = 0; j < 4; ++j) {
            int r = rbase + j;
            if (r < n) {
#pragma unroll
                for (int nt = 0; nt < 4; ++nt)
                    h[(size_t)r * DF + n0 + nt * 16 + lr] = __float2half(acc[mt][nt][j]);
            }
        }
    }
}

// ---------------- Aggregation: XCD-quartered feature gather ----------------
// Feature dim split into 4 x 64B quarters; quarter = (bid&7)>>1 so XCD pair
// {2q,2q+1} only touches quarter q -> per-XCD h working set 3.2MB (L2-fits).
// Wave = 2 nodes (A/B chains). Gather: 4 lanes x 16B per quarter-row -> ONE
// instruction covers 16 rows. csr chunk loads lane-clamped (dupes free under
// max); ids broadcast by __shfl. Reduce across row-slots via xor 4/8/16/32.

__global__ __launch_bounds__(256) void agg_kernel(const __half* __restrict__ hin,
        const int* __restrict__ off, const unsigned short* __restrict__ csr,
        float* __restrict__ out, _Float16* __restrict__ xf, int n, int split) {
    int wid = threadIdx.x >> 6;
    int lane = threadIdx.x & 63;
    int bid = blockIdx.x;
    int q = (bid & 7) >> 1;                     // feature quarter (XCD pair)
    int idx = ((bid >> 3) << 1) | (bid & 1);    // within-quarter block index
    int nodeA = idx * 8 + wid * 2;
    if (nodeA >= n) return;
    int nodeB = nodeA + 1;
    bool hasB = (nodeB < n);

    int r = lane >> 2;           // row slot 0..15
    int c2 = lane & 3;           // 16B column within 64B quarter
    int qb = q * 64 + c2 * 16;   // byte offset within 256B row

    int begA = off[nodeA], endA = off[nodeA + 1];
    int begB = hasB ? off[nodeB] : 0;
    int endB = hasB ? off[nodeB + 1] : 0;
    int degA = endA - begA, degB = endB - begB;
    int e1A = endA - 1, e1B = endB - 1;

    unsigned a0 = 0xFC00FC00u, a1 = a0, a2 = a0, a3 = a0;
    unsigned b0 = a0, b1 = a0, b2 = a0, b3 = a0;

    int nch = max((degA + 63) >> 6, (degB + 63) >> 6);
    for (int ch = 0; ch < nch; ++ch) {
        int baseo = ch << 6;
        bool doA = baseo < degA, doB = baseo < degB;
        int idA = 0, idB = 0;
        if (doA) idA = csr[min(begA + baseo + lane, e1A)];
        if (doB) idB = csr[min(begB + baseo + lane, e1B)];
        int limA = doA ? min(degA - baseo, 64) : 0;
        int limB = doB ? min(degB - baseo, 64) : 0;
        int lim = max(limA, limB);
        for (int t = 0; t < lim; t += 16) {
            if (t < limA) {
                int i0 = __shfl(idA, t + r);
                uint4 g = *(const uint4*)((const char*)hin + ((size_t)i0 << 8) + qb);
                a0 = pkmax(a0, g.x); a1 = pkmax(a1, g.y);
                a2 = pkmax(a2, g.z); a3 = pkmax(a3, g.w);
            }
            if (t < limB) {
                int i0 = __shfl(idB, t + r);
                uint4 g = *(const uint4*)((const char*)hin + ((size_t)i0 << 8) + qb);
                b0 = pkmax(b0, g.x); b1 = pkmax(b1, g.y);
                b2 = pkmax(b2, g.z); b3 = pkmax(b3, g.w);
            }
        }
    }

    // reduce across the 16 row slots (xor strides 4,8,16,32)
#pragma unroll
    for (int d = 4; d <= 32; d <<= 1) {
        a0 = pkmax(a0, (unsigned)__shfl_xor((int)a0, d));
        a1 = pkmax(a1, (unsigned)__shfl_xor((int)a1, d));
        a2 = pkmax(a2, (unsigned)__shfl_xor((int)a2, d));
        a3 = pkmax(a3, (unsigned)__shfl_xor((int)a3, d));
        b0 = pkmax(b0, (unsigned)__shfl_xor((int)b0, d));
        b1 = pkmax(b1, (unsigned)__shfl_xor((int)b1, d));
        b2 = pkmax(b2, (unsigned)__shfl_xor((int)b2, d));
        b3 = pkmax(b3, (unsigned)__shfl_xor((int)b3, d));
    }

    // epilogue: row slot 0 -> node A, row slot 1 -> node B (4 lanes each)
    int myNode; unsigned r0, r1, r2, r3; bool empty;
    if (r == 0) {
        myNode = nodeA; r0 = a0; r1 = a1; r2 = a2; r3 = a3; empty = (degA == 0);
    } else if (r == 1 && hasB) {
        myNode = nodeB; r0 = b0; r1 = b1; r2 = b2; r3 = b3; empty = (degB == 0);
    } else {
        return;
    }

    float f[8];
    f[0] = h2f((unsigned short)(r0 & 0xFFFF)); f[1] = h2f((unsigned short)(r0 >> 16));
    f[2] = h2f((unsigned short)(r1 & 0xFFFF)); f[3] = h2f((unsigned short)(r1 >> 16));
    f[4] = h2f((unsigned short)(r2 & 0xFFFF)); f[5] = h2f((unsigned short)(r2 >> 16));
    f[6] = h2f((unsigned short)(r3 & 0xFFFF)); f[7] = h2f((unsigned short)(r3 >> 16));
    if (empty) {
#pragma unroll
        for (int j = 0; j < 8; ++j) f[j] = 0.0f;
    }

    if (split) {
        f16x8 v;
#pragma unroll
        for (int j = 0; j < 8; ++j) v[j] = (_Float16)silu(f[j]);
        *reinterpret_cast<f16x8*>(xf + (size_t)myNode * DF + q * 32 + c2 * 8) = v;
    } else {
        float4* o = (float4*)(out + (size_t)myNode * DF + q * 32 + c2 * 8);
        o[0] = make_float4(f[0], f[1], f[2], f[3]);
        o[1] = make_float4(f[4], f[5], f[6], f[7]);
    }
}

// ---------------- Launch ----------------

extern "C" void kernel_launch(void* const* d_in, const int* in_sizes, int n_in,
                              void* d_out, int out_size, void* d_ws, size_t ws_size,
                              hipStream_t stream) {
    const float* x  = (const float*)d_in[0];
    const int*   ei = (const int*)d_in[1];
    const float* Ws = (const float*)d_in[2];
    const float* bs = (const float*)d_in[3];
    float* out = (float*)d_out;

    int N = in_sizes[0] / DF;
    int E = in_sizes[1] / 2;
    const int* src = ei;
    const int* dst = ei + E;

    char* w = (char*)d_ws;
    auto carve = [&](size_t bytes) {
        char* p = w;
        w += (bytes + 255) & ~(size_t)255;
        return p;
    };
    int nb = (N + 255) / 256;
    int*            cnt  = (int*)carve((size_t)(N + 1) * sizeof(int));
    int*            off  = (int*)carve((size_t)(N + 1) * sizeof(int));
    int*            bsum = (int*)carve((size_t)nb * sizeof(int));
    unsigned short* rank = (unsigned short*)carve((size_t)E * sizeof(unsigned short));
    unsigned short* csr  = (unsigned short*)carve((size_t)E * sizeof(unsigned short));
    __half*         h    = (__half*)carve((size_t)N * DF * sizeof(__half));
    _Float16*       xf   = (_Float16*)carve((size_t)N * DF * sizeof(_Float16));
    _Float16*       whf  = (_Float16*)carve((size_t)NLAYERS * DF * DF * sizeof(_Float16));
    _Float16*       wlf  = (_Float16*)carve((size_t)NLAYERS * DF * DF * sizeof(_Float16));

    int nbE = (E + 255) / 256;
    int wt4 = NLAYERS * DF * DF / 4;
    int nbW = (wt4 + 255) / 256;
    int ggrid = (N + 63) / 64;
    // agg grid: 4 quarters x (within-quarter blocks of 8 nodes)
    int ngrp = (N + 7) / 8;
    int agrid = 8 * ((ngrp + 1) / 2);

    // ---- CSR build + W fp16-pair split ----
    zero_kernel<<<nb, 256, 0, stream>>>(cnt, N);
    prep_kernel<<<nbE + nbW, 256, 0, stream>>>(dst, cnt, rank, E, nbE, Ws, whf, wlf, wt4);
    partial_sum_kernel<<<nb, 256, 0, stream>>>(cnt, bsum, N);
    scan_scatter_kernel<<<nb, 256, 0, stream>>>(cnt, bsum, off, N, E, nb);

    // ---- CSR fill co-launched with layer-0 gemm ----
    fill_gemm0_kernel<<<nbE + ggrid, 256, 0, stream>>>(
        src, dst, off, rank, csr, E, nbE, x, whf, wlf, bs, h, N);

    // ---- layers 1..4: agg -> xf (SiLU, fp16), gemm -> h; final agg -> out ----
    for (int layer = 1; layer < NLAYERS; ++layer) {
        agg_kernel<<<agrid, 256, 0, stream>>>(h, off, csr, out, xf, N, 1);
        const _Float16* whl = whf + (size_t)layer * DF * DF;
        const _Float16* wll = wlf + (size_t)layer * DF * DF;
        const float* bl = bs + (size_t)layer * DF;
        gemm_f16_kernel<<<ggrid, 256, 0, stream>>>(xf, whl, wll, bl, h, N);
    }
    agg_kernel<<<agrid, 256, 0, stream>>>(h, off, csr, out, NULL, N, 0);
}

// Round 16
// 375.306 us; speedup vs baseline: 1.2669x; 1.2669x over previous
//
#include <hip/hip_runtime.h>
#include <hip/hip_bf16.h>
#include <hip/hip_fp16.h>
#include <math.h>

#define DF 128          // feature dim
#define NLAYERS 5

typedef __attribute__((ext_vector_type(8))) _Float16 f16x8;
typedef __attribute__((ext_vector_type(4))) _Float16 f16x4;
typedef __attribute__((ext_vector_type(4))) float f32x4;
typedef __attribute__((ext_vector_type(4))) unsigned u32x4;

// packed fp16 max on raw bits (ROCm 7.2 lacks a viable fp16 __hmax2 overload)
__device__ inline unsigned pkmax(unsigned a, unsigned b) {
    unsigned d;
    asm("v_pk_max_f16 %0, %1, %2" : "=v"(d) : "v"(a), "v"(b));
    return d;
}
__device__ inline float h2f(unsigned short u) {
    __half_raw r; r.x = u;
    return __half2float(__half(r));
}
__device__ inline float silu(float v) {
    return v * (1.0f / (1.0f + __expf(-v)));
}

// split 8 consecutive fp32 into fp16 hi + fp16 lo (hi+lo ~ 2^-22 accurate)
__device__ inline void split8f(const float* p, f16x8& hi, f16x8& lo) {
    float4 v0 = *reinterpret_cast<const float4*>(p);
    float4 v1 = *reinterpret_cast<const float4*>(p + 4);
    float f[8] = {v0.x, v0.y, v0.z, v0.w, v1.x, v1.y, v1.z, v1.w};
#pragma unroll
    for (int j = 0; j < 8; ++j) {
        _Float16 a = (_Float16)f[j];
        hi[j] = a;
        lo[j] = (_Float16)(f[j] - (float)a);
    }
}

// ---------------- zero cnt ----------------

__global__ __launch_bounds__(256) void zero_kernel(int* __restrict__ p, int n) {
    int i = blockIdx.x * 256 + threadIdx.x;
    if (i < n) p[i] = 0;
}

// ---------------- prep: histogram+rank (blocks [0,nbE)) | W->fp16 pair (rest) --

__global__ __launch_bounds__(256) void prep_kernel(const int* __restrict__ dst,
        int* __restrict__ cnt, unsigned short* __restrict__ rank, int E, int nbE,
        const float* __restrict__ Ws, _Float16* __restrict__ whf,
        _Float16* __restrict__ wlf, int wt4) {
    int b = blockIdx.x;
    int t = threadIdx.x;
    if (b < nbE) {
        int i = b * 256 + t;
        if (i < E) rank[i] = (unsigned short)atomicAdd(&cnt[dst[i]], 1);
    } else {
        int i = (b - nbE) * 256 + t;
        if (i < wt4) {
            float4 v = reinterpret_cast<const float4*>(Ws)[i];
            float f[4] = {v.x, v.y, v.z, v.w};
            f16x4 h, l;
#pragma unroll
            for (int j = 0; j < 4; ++j) {
                _Float16 a = (_Float16)f[j];
                h[j] = a;
                l[j] = (_Float16)(f[j] - (float)a);
            }
            reinterpret_cast<f16x4*>(whf)[i] = h;
            reinterpret_cast<f16x4*>(wlf)[i] = l;
        }
    }
}

// ---------------- CSR scan chain ----------------

__global__ __launch_bounds__(256) void partial_sum_kernel(const int* __restrict__ cnt,
        int* __restrict__ bsum, int n) {
    __shared__ int red[256];
    int t = threadIdx.x;
    int i = blockIdx.x * 256 + t;
    red[t] = (i < n) ? cnt[i] : 0;
    __syncthreads();
    for (int d = 128; d > 0; d >>= 1) {
        if (t < d) red[t] += red[t + d];
        __syncthreads();
    }
    if (t == 0) bsum[blockIdx.x] = red[0];
}

__global__ __launch_bounds__(256) void scan_scatter_kernel(const int* __restrict__ cnt,
        const int* __restrict__ bsum, int* __restrict__ off, int n, int E, int nb) {
    __shared__ int sb[256];
    __shared__ int s[256];
    int t = threadIdx.x;
    int bv = (t < nb) ? bsum[t] : 0;
    sb[t] = bv;
    __syncthreads();
    for (int d = 1; d < 256; d <<= 1) {
        int u = (t >= d) ? sb[t - d] : 0;
        __syncthreads();
        sb[t] += u;
        __syncthreads();
    }
    int base = (blockIdx.x > 0) ? sb[blockIdx.x - 1] : 0;
    int i = blockIdx.x * 256 + t;
    int v = (i < n) ? cnt[i] : 0;
    s[t] = v;
    __syncthreads();
    for (int d = 1; d < 256; d <<= 1) {
        int u = (t >= d) ? s[t - d] : 0;
        __syncthreads();
        s[t] += u;
        __syncthreads();
    }
    int excl = s[t] - v + base;
    if (i < n) off[i] = excl;
    if (blockIdx.x == 0 && t == 0) off[n] = E;
}

// ---------------- fused: CSR fill (ushort) | layer-0 GEMM f16 ----------------

__global__ __launch_bounds__(256, 3) void fill_gemm0_kernel(
        const int* __restrict__ src, const int* __restrict__ dst,
        const int* __restrict__ off, const unsigned short* __restrict__ rank,
        unsigned short* __restrict__ csr, int E, int nbE,
        const float* __restrict__ x,
        const _Float16* __restrict__ whf, const _Float16* __restrict__ wlf,
        const float* __restrict__ bias, __half* __restrict__ h, int n) {
    if (blockIdx.x < nbE) {
        int i = blockIdx.x * 256 + threadIdx.x;
        if (i < E) csr[off[dst[i]] + (int)rank[i]] = (unsigned short)src[i];
        return;
    }
    int bid = blockIdx.x - nbE;

    int wave = threadIdx.x >> 6;
    int lane = threadIdx.x & 63;
    int wm = wave >> 1;
    int wn = wave & 1;
    int m0 = bid * 64 + wm * 32;
    int n0 = wn * 64;
    int lr = lane & 15;
    int lk = lane >> 4;

    f32x4 acc[2][4];
#pragma unroll
    for (int mt = 0; mt < 2; ++mt)
#pragma unroll
        for (int nt = 0; nt < 4; ++nt) {
            float bv = bias[n0 + nt * 16 + lr];
            acc[mt][nt] = (f32x4){bv, bv, bv, bv};
        }

    int rowA0 = min(m0 + lr, n - 1);
    int rowA1 = min(m0 + 16 + lr, n - 1);

#pragma unroll
    for (int ks = 0; ks < 4; ++ks) {
        int ko = ks * 32 + lk * 8;
        f16x8 a0h, a0l, a1h, a1l;
        split8f(x + (size_t)rowA0 * DF + ko, a0h, a0l);
        split8f(x + (size_t)rowA1 * DF + ko, a1h, a1l);
#pragma unroll
        for (int nt = 0; nt < 4; ++nt) {
            int ncol = n0 + nt * 16 + lr;
            f16x8 wh = *(const f16x8*)(whf + ncol * DF + ko);
            f16x8 wl = *(const f16x8*)(wlf + ncol * DF + ko);
            acc[0][nt] = __builtin_amdgcn_mfma_f32_16x16x32_f16(a0h, wh, acc[0][nt], 0, 0, 0);
            acc[0][nt] = __builtin_amdgcn_mfma_f32_16x16x32_f16(a0l, wh, acc[0][nt], 0, 0, 0);
            acc[0][nt] = __builtin_amdgcn_mfma_f32_16x16x32_f16(a0h, wl, acc[0][nt], 0, 0, 0);
            acc[1][nt] = __builtin_amdgcn_mfma_f32_16x16x32_f16(a1h, wh, acc[1][nt], 0, 0, 0);
            acc[1][nt] = __builtin_amdgcn_mfma_f32_16x16x32_f16(a1l, wh, acc[1][nt], 0, 0, 0);
            acc[1][nt] = __builtin_amdgcn_mfma_f32_16x16x32_f16(a1h, wl, acc[1][nt], 0, 0, 0);
        }
    }

#pragma unroll
    for (int mt = 0; mt < 2; ++mt) {
        int rbase = m0 + mt * 16 + lk * 4;
#pragma unroll
        for (int j = 0; j < 4; ++j) {
            int r = rbase + j;
            if (r < n) {
#pragma unroll
                for (int nt = 0; nt < 4; ++nt)
                    h[(size_t)r * DF + n0 + nt * 16 + lr] = __float2half(acc[mt][nt][j]);
            }
        }
    }
}

// ---------------- GEMM layers 1-4: A = fp16 x (exact), B = fp16 W pair --------

__global__ __launch_bounds__(256, 3) void gemm_f16_kernel(
        const _Float16* __restrict__ xf,
        const _Float16* __restrict__ whf, const _Float16* __restrict__ wlf,
        const float* __restrict__ bias, __half* __restrict__ h, int n) {
    int wave = threadIdx.x >> 6;
    int lane = threadIdx.x & 63;
    int wm = wave >> 1;
    int wn = wave & 1;
    int m0 = blockIdx.x * 64 + wm * 32;
    int n0 = wn * 64;
    int lr = lane & 15;
    int lk = lane >> 4;

    f32x4 acc[2][4];
#pragma unroll
    for (int mt = 0; mt < 2; ++mt)
#pragma unroll
        for (int nt = 0; nt < 4; ++nt) {
            float bv = bias[n0 + nt * 16 + lr];
            acc[mt][nt] = (f32x4){bv, bv, bv, bv};
        }

    int rowA0 = min(m0 + lr, n - 1);
    int rowA1 = min(m0 + 16 + lr, n - 1);

#pragma unroll
    for (int ks = 0; ks < 4; ++ks) {
        int ko = ks * 32 + lk * 8;
        f16x8 a0 = *(const f16x8*)(xf + (size_t)rowA0 * DF + ko);
        f16x8 a1 = *(const f16x8*)(xf + (size_t)rowA1 * DF + ko);
#pragma unroll
        for (int nt = 0; nt < 4; ++nt) {
            int ncol = n0 + nt * 16 + lr;
            f16x8 wh = *(const f16x8*)(whf + ncol * DF + ko);
            f16x8 wl = *(const f16x8*)(wlf + ncol * DF + ko);
            acc[0][nt] = __builtin_amdgcn_mfma_f32_16x16x32_f16(a0, wh, acc[0][nt], 0, 0, 0);
            acc[0][nt] = __builtin_amdgcn_mfma_f32_16x16x32_f16(a0, wl, acc[0][nt], 0, 0, 0);
            acc[1][nt] = __builtin_amdgcn_mfma_f32_16x16x32_f16(a1, wh, acc[1][nt], 0, 0, 0);
            acc[1][nt] = __builtin_amdgcn_mfma_f32_16x16x32_f16(a1, wl, acc[1][nt], 0, 0, 0);
        }
    }

#pragma unroll
    for (int mt = 0; mt < 2; ++mt) {
        int rbase = m0 + mt * 16 + lk * 4;
#pragma unroll
        for (int j = 0; j < 4; ++j) {
            int r = rbase + j;
            if (r < n) {
#pragma unroll
                for (int nt = 0; nt < 4; ++nt)
                    h[(size_t)r * DF + n0 + nt * 16 + lr] = __float2half(acc[mt][nt][j]);
            }
        }
    }
}

// ---------------- Aggregation (R12 structure + nontemporal gathers) ----------
// One wave per node. Per 64-edge chunk: ONE coalesced csr load (clamped =
// dupe-safe under max), ids broadcast via __shfl, then u32x4 gathers: 16 lanes
// x 16B per row -> 4 rows per VMEM instruction, 4 independent gathers per
// 16-edge step. Gathers are nontemporal (random over 12.8MB; L1 useless).

__global__ __launch_bounds__(256) void agg_kernel(const __half* __restrict__ hin,
        const int* __restrict__ off, const unsigned short* __restrict__ csr,
        float* __restrict__ out, _Float16* __restrict__ xf, int n, int split) {
    int wid = threadIdx.x >> 6;
    int lane = threadIdx.x & 63;
    int node = blockIdx.x * 4 + wid;
    if (node >= n) return;

    int q = lane >> 4;           // quarter: which of 4 edges in a 16-edge step
    int c = lane & 15;           // 16B column within 256B row

    int beg = off[node];
    int end = off[node + 1];

    unsigned m0 = 0xFC00FC00u, m1 = m0, m2 = m0, m3 = m0;

    if (beg < end) {
        int e1 = end - 1;
        int deg = end - beg;
        for (int base = 0; base < deg; base += 64) {
            int myid = csr[min(beg + base + lane, e1)];
            int lim = min(deg - base, 64);
            for (int t = 0; t < lim; t += 16) {
                int i0 = __shfl(myid, t + q);
                int i1 = __shfl(myid, t + q + 4);
                int i2 = __shfl(myid, t + q + 8);
                int i3 = __shfl(myid, t + q + 12);
                u32x4 a = __builtin_nontemporal_load(
                    (const u32x4*)((const char*)hin + ((size_t)i0 << 8) + (c << 4)));
                u32x4 b = __builtin_nontemporal_load(
                    (const u32x4*)((const char*)hin + ((size_t)i1 << 8) + (c << 4)));
                u32x4 d = __builtin_nontemporal_load(
                    (const u32x4*)((const char*)hin + ((size_t)i2 << 8) + (c << 4)));
                u32x4 e = __builtin_nontemporal_load(
                    (const u32x4*)((const char*)hin + ((size_t)i3 << 8) + (c << 4)));
                m0 = pkmax(m0, pkmax(pkmax(a.x, b.x), pkmax(d.x, e.x)));
                m1 = pkmax(m1, pkmax(pkmax(a.y, b.y), pkmax(d.y, e.y)));
                m2 = pkmax(m2, pkmax(pkmax(a.z, b.z), pkmax(d.z, e.z)));
                m3 = pkmax(m3, pkmax(pkmax(a.w, b.w), pkmax(d.w, e.w)));
            }
        }
        // reduce across quarters (lane i <-> i^16, i^32)
        m0 = pkmax(m0, (unsigned)__shfl_xor((int)m0, 16));
        m0 = pkmax(m0, (unsigned)__shfl_xor((int)m0, 32));
        m1 = pkmax(m1, (unsigned)__shfl_xor((int)m1, 16));
        m1 = pkmax(m1, (unsigned)__shfl_xor((int)m1, 32));
        m2 = pkmax(m2, (unsigned)__shfl_xor((int)m2, 16));
        m2 = pkmax(m2, (unsigned)__shfl_xor((int)m2, 32));
        m3 = pkmax(m3, (unsigned)__shfl_xor((int)m3, 16));
        m3 = pkmax(m3, (unsigned)__shfl_xor((int)m3, 32));
    }

    if (q != 0) return;

    float f[8];
    f[0] = h2f((unsigned short)(m0 & 0xFFFF)); f[1] = h2f((unsigned short)(m0 >> 16));
    f[2] = h2f((unsigned short)(m1 & 0xFFFF)); f[3] = h2f((unsigned short)(m1 >> 16));
    f[4] = h2f((unsigned short)(m2 & 0xFFFF)); f[5] = h2f((unsigned short)(m2 >> 16));
    f[6] = h2f((unsigned short)(m3 & 0xFFFF)); f[7] = h2f((unsigned short)(m3 >> 16));
    if (beg == end) {
#pragma unroll
        for (int j = 0; j < 8; ++j) f[j] = 0.0f;
    }

    if (split) {
        f16x8 v;
#pragma unroll
        for (int j = 0; j < 8; ++j) v[j] = (_Float16)silu(f[j]);
        *reinterpret_cast<f16x8*>(xf + (size_t)node * DF + c * 8) = v;
    } else {
        float4* o = (float4*)(out + (size_t)node * DF + c * 8);
        o[0] = make_float4(f[0], f[1], f[2], f[3]);
        o[1] = make_float4(f[4], f[5], f[6], f[7]);
    }
}

// ---------------- Launch ----------------

extern "C" void kernel_launch(void* const* d_in, const int* in_sizes, int n_in,
                              void* d_out, int out_size, void* d_ws, size_t ws_size,
                              hipStream_t stream) {
    const float* x  = (const float*)d_in[0];
    const int*   ei = (const int*)d_in[1];
    const float* Ws = (const float*)d_in[2];
    const float* bs = (const float*)d_in[3];
    float* out = (float*)d_out;

    int N = in_sizes[0] / DF;
    int E = in_sizes[1] / 2;
    const int* src = ei;
    const int* dst = ei + E;

    char* w = (char*)d_ws;
    auto carve = [&](size_t bytes) {
        char* p = w;
        w += (bytes + 255) & ~(size_t)255;
        return p;
    };
    int nb = (N + 255) / 256;
    int*            cnt  = (int*)carve((size_t)(N + 1) * sizeof(int));
    int*            off  = (int*)carve((size_t)(N + 1) * sizeof(int));
    int*            bsum = (int*)carve((size_t)nb * sizeof(int));
    unsigned short* rank = (unsigned short*)carve((size_t)E * sizeof(unsigned short));
    unsigned short* csr  = (unsigned short*)carve((size_t)E * sizeof(unsigned short));
    __half*         h    = (__half*)carve((size_t)N * DF * sizeof(__half));
    _Float16*       xf   = (_Float16*)carve((size_t)N * DF * sizeof(_Float16));
    _Float16*       whf  = (_Float16*)carve((size_t)NLAYERS * DF * DF * sizeof(_Float16));
    _Float16*       wlf  = (_Float16*)carve((size_t)NLAYERS * DF * DF * sizeof(_Float16));

    int nbE = (E + 255) / 256;
    int wt4 = NLAYERS * DF * DF / 4;
    int nbW = (wt4 + 255) / 256;
    int ggrid = (N + 63) / 64;
    int agrid = (N + 3) / 4;

    // ---- CSR build + W fp16-pair split ----
    zero_kernel<<<nb, 256, 0, stream>>>(cnt, N);
    prep_kernel<<<nbE + nbW, 256, 0, stream>>>(dst, cnt, rank, E, nbE, Ws, whf, wlf, wt4);
    partial_sum_kernel<<<nb, 256, 0, stream>>>(cnt, bsum, N);
    scan_scatter_kernel<<<nb, 256, 0, stream>>>(cnt, bsum, off, N, E, nb);

    // ---- CSR fill co-launched with layer-0 gemm ----
    fill_gemm0_kernel<<<nbE + ggrid, 256, 0, stream>>>(
        src, dst, off, rank, csr, E, nbE, x, whf, wlf, bs, h, N);

    // ---- layers 1..4: agg -> xf (SiLU, fp16), gemm -> h; final agg -> out ----
    for (int layer = 1; layer < NLAYERS; ++layer) {
        agg_kernel<<<agrid, 256, 0, stream>>>(h, off, csr, out, xf, N, 1);
        const _Float16* whl = whf + (size_t)layer * DF * DF;
        const _Float16* wll = wlf + (size_t)layer * DF * DF;
        const float* bl = bs + (size_t)layer * DF;
        gemm_f16_kernel<<<ggrid, 256, 0, stream>>>(xf, whl, wll, bl, h, N);
    }
    agg_kernel<<<agrid, 256, 0, stream>>>(h, off, csr, out, NULL, N, 0);
}

// Round 17
// 323.461 us; speedup vs baseline: 1.4700x; 1.1603x over previous
//
#include <hip/hip_runtime.h>
#include <hip/hip_bf16.h>
#include <hip/hip_fp16.h>
#include <math.h>

#define DF 128          // feature dim
#define NLAYERS 5

typedef __attribute__((ext_vector_type(8))) _Float16 f16x8;
typedef __attribute__((ext_vector_type(4))) _Float16 f16x4;
typedef __attribute__((ext_vector_type(4))) float f32x4;

// packed fp16 max on raw bits (ROCm 7.2 lacks a viable fp16 __hmax2 overload)
__device__ inline unsigned pkmax(unsigned a, unsigned b) {
    unsigned d;
    asm("v_pk_max_f16 %0, %1, %2" : "=v"(d) : "v"(a), "v"(b));
    return d;
}
__device__ inline float h2f(unsigned short u) {
    __half_raw r; r.x = u;
    return __half2float(__half(r));
}
__device__ inline float silu(float v) {
    return v * (1.0f / (1.0f + __expf(-v)));
}

// split 8 consecutive fp32 into fp16 hi + fp16 lo (hi+lo ~ 2^-22 accurate)
__device__ inline void split8f(const float* p, f16x8& hi, f16x8& lo) {
    float4 v0 = *reinterpret_cast<const float4*>(p);
    float4 v1 = *reinterpret_cast<const float4*>(p + 4);
    float f[8] = {v0.x, v0.y, v0.z, v0.w, v1.x, v1.y, v1.z, v1.w};
#pragma unroll
    for (int j = 0; j < 8; ++j) {
        _Float16 a = (_Float16)f[j];
        hi[j] = a;
        lo[j] = (_Float16)(f[j] - (float)a);
    }
}

// ---------------- zero cnt ----------------

__global__ __launch_bounds__(256) void zero_kernel(int* __restrict__ p, int n) {
    int i = blockIdx.x * 256 + threadIdx.x;
    if (i < n) p[i] = 0;
}

// ---------------- prep: histogram+rank (blocks [0,nbE)) | W->fp16 pair (rest) --

__global__ __launch_bounds__(256) void prep_kernel(const int* __restrict__ dst,
        int* __restrict__ cnt, unsigned short* __restrict__ rank, int E, int nbE,
        const float* __restrict__ Ws, _Float16* __restrict__ whf,
        _Float16* __restrict__ wlf, int wt4) {
    int b = blockIdx.x;
    int t = threadIdx.x;
    if (b < nbE) {
        int i = b * 256 + t;
        if (i < E) rank[i] = (unsigned short)atomicAdd(&cnt[dst[i]], 1);
    } else {
        int i = (b - nbE) * 256 + t;
        if (i < wt4) {
            float4 v = reinterpret_cast<const float4*>(Ws)[i];
            float f[4] = {v.x, v.y, v.z, v.w};
            f16x4 h, l;
#pragma unroll
            for (int j = 0; j < 4; ++j) {
                _Float16 a = (_Float16)f[j];
                h[j] = a;
                l[j] = (_Float16)(f[j] - (float)a);
            }
            reinterpret_cast<f16x4*>(whf)[i] = h;
            reinterpret_cast<f16x4*>(wlf)[i] = l;
        }
    }
}

// ---------------- CSR scan chain ----------------

__global__ __launch_bounds__(256) void partial_sum_kernel(const int* __restrict__ cnt,
        int* __restrict__ bsum, int n) {
    __shared__ int red[256];
    int t = threadIdx.x;
    int i = blockIdx.x * 256 + t;
    red[t] = (i < n) ? cnt[i] : 0;
    __syncthreads();
    for (int d = 128; d > 0; d >>= 1) {
        if (t < d) red[t] += red[t + d];
        __syncthreads();
    }
    if (t == 0) bsum[blockIdx.x] = red[0];
}

__global__ __launch_bounds__(256) void scan_scatter_kernel(const int* __restrict__ cnt,
        const int* __restrict__ bsum, int* __restrict__ off, int n, int E, int nb) {
    __shared__ int sb[256];
    __shared__ int s[256];
    int t = threadIdx.x;
    int bv = (t < nb) ? bsum[t] : 0;
    sb[t] = bv;
    __syncthreads();
    for (int d = 1; d < 256; d <<= 1) {
        int u = (t >= d) ? sb[t - d] : 0;
        __syncthreads();
        sb[t] += u;
        __syncthreads();
    }
    int base = (blockIdx.x > 0) ? sb[blockIdx.x - 1] : 0;
    int i = blockIdx.x * 256 + t;
    int v = (i < n) ? cnt[i] : 0;
    s[t] = v;
    __syncthreads();
    for (int d = 1; d < 256; d <<= 1) {
        int u = (t >= d) ? s[t - d] : 0;
        __syncthreads();
        s[t] += u;
        __syncthreads();
    }
    int excl = s[t] - v + base;
    if (i < n) off[i] = excl;
    if (blockIdx.x == 0 && t == 0) off[n] = E;
}

// ---------------- fused: CSR fill (ushort) | layer-0 GEMM f16 ----------------

__global__ __launch_bounds__(256, 3) void fill_gemm0_kernel(
        const int* __restrict__ src, const int* __restrict__ dst,
        const int* __restrict__ off, const unsigned short* __restrict__ rank,
        unsigned short* __restrict__ csr, int E, int nbE,
        const float* __restrict__ x,
        const _Float16* __restrict__ whf, const _Float16* __restrict__ wlf,
        const float* __restrict__ bias, __half* __restrict__ h, int n) {
    if (blockIdx.x < nbE) {
        int i = blockIdx.x * 256 + threadIdx.x;
        if (i < E) csr[off[dst[i]] + (int)rank[i]] = (unsigned short)src[i];
        return;
    }
    int bid = blockIdx.x - nbE;

    int wave = threadIdx.x >> 6;
    int lane = threadIdx.x & 63;
    int wm = wave >> 1;
    int wn = wave & 1;
    int m0 = bid * 64 + wm * 32;
    int n0 = wn * 64;
    int lr = lane & 15;
    int lk = lane >> 4;

    f32x4 acc[2][4];
#pragma unroll
    for (int mt = 0; mt < 2; ++mt)
#pragma unroll
        for (int nt = 0; nt < 4; ++nt) {
            float bv = bias[n0 + nt * 16 + lr];
            acc[mt][nt] = (f32x4){bv, bv, bv, bv};
        }

    int rowA0 = min(m0 + lr, n - 1);
    int rowA1 = min(m0 + 16 + lr, n - 1);

#pragma unroll
    for (int ks = 0; ks < 4; ++ks) {
        int ko = ks * 32 + lk * 8;
        f16x8 a0h, a0l, a1h, a1l;
        split8f(x + (size_t)rowA0 * DF + ko, a0h, a0l);
        split8f(x + (size_t)rowA1 * DF + ko, a1h, a1l);
#pragma unroll
        for (int nt = 0; nt < 4; ++nt) {
            int ncol = n0 + nt * 16 + lr;
            f16x8 wh = *(const f16x8*)(whf + ncol * DF + ko);
            f16x8 wl = *(const f16x8*)(wlf + ncol * DF + ko);
            acc[0][nt] = __builtin_amdgcn_mfma_f32_16x16x32_f16(a0h, wh, acc[0][nt], 0, 0, 0);
            acc[0][nt] = __builtin_amdgcn_mfma_f32_16x16x32_f16(a0l, wh, acc[0][nt], 0, 0, 0);
            acc[0][nt] = __builtin_amdgcn_mfma_f32_16x16x32_f16(a0h, wl, acc[0][nt], 0, 0, 0);
            acc[1][nt] = __builtin_amdgcn_mfma_f32_16x16x32_f16(a1h, wh, acc[1][nt], 0, 0, 0);
            acc[1][nt] = __builtin_amdgcn_mfma_f32_16x16x32_f16(a1l, wh, acc[1][nt], 0, 0, 0);
            acc[1][nt] = __builtin_amdgcn_mfma_f32_16x16x32_f16(a1h, wl, acc[1][nt], 0, 0, 0);
        }
    }

#pragma unroll
    for (int mt = 0; mt < 2; ++mt) {
        int rbase = m0 + mt * 16 + lk * 4;
#pragma unroll
        for (int j = 0; j < 4; ++j) {
            int r = rbase + j;
            if (r < n) {
#pragma unroll
                for (int nt = 0; nt < 4; ++nt)
                    h[(size_t)r * DF + n0 + nt * 16 + lr] = __float2half(acc[mt][nt][j]);
            }
        }
    }
}

// ---------------- GEMM layers 1-4: A = fp16 x (exact), B = fp16 W pair --------

__global__ __launch_bounds__(256, 3) void gemm_f16_kernel(
        const _Float16* __restrict__ xf,
        const _Float16* __restrict__ whf, const _Float16* __restrict__ wlf,
        const float* __restrict__ bias, __half* __restrict__ h, int n) {
    int wave = threadIdx.x >> 6;
    int lane = threadIdx.x & 63;
    int wm = wave >> 1;
    int wn = wave & 1;
    int m0 = blockIdx.x * 64 + wm * 32;
    int n0 = wn * 64;
    int lr = lane & 15;
    int lk = lane >> 4;

    f32x4 acc[2][4];
#pragma unroll
    for (int mt = 0; mt < 2; ++mt)
#pragma unroll
        for (int nt = 0; nt < 4; ++nt) {
            float bv = bias[n0 + nt * 16 + lr];
            acc[mt][nt] = (f32x4){bv, bv, bv, bv};
        }

    int rowA0 = min(m0 + lr, n - 1);
    int rowA1 = min(m0 + 16 + lr, n - 1);

#pragma unroll
    for (int ks = 0; ks < 4; ++ks) {
        int ko = ks * 32 + lk * 8;
        f16x8 a0 = *(const f16x8*)(xf + (size_t)rowA0 * DF + ko);
        f16x8 a1 = *(const f16x8*)(xf + (size_t)rowA1 * DF + ko);
#pragma unroll
        for (int nt = 0; nt < 4; ++nt) {
            int ncol = n0 + nt * 16 + lr;
            f16x8 wh = *(const f16x8*)(whf + ncol * DF + ko);
            f16x8 wl = *(const f16x8*)(wlf + ncol * DF + ko);
            acc[0][nt] = __builtin_amdgcn_mfma_f32_16x16x32_f16(a0, wh, acc[0][nt], 0, 0, 0);
            acc[0][nt] = __builtin_amdgcn_mfma_f32_16x16x32_f16(a0, wl, acc[0][nt], 0, 0, 0);
            acc[1][nt] = __builtin_amdgcn_mfma_f32_16x16x32_f16(a1, wh, acc[1][nt], 0, 0, 0);
            acc[1][nt] = __builtin_amdgcn_mfma_f32_16x16x32_f16(a1, wl, acc[1][nt], 0, 0, 0);
        }
    }

#pragma unroll
    for (int mt = 0; mt < 2; ++mt) {
        int rbase = m0 + mt * 16 + lk * 4;
#pragma unroll
        for (int j = 0; j < 4; ++j) {
            int r = rbase + j;
            if (r < n) {
#pragma unroll
                for (int nt = 0; nt < 4; ++nt)
                    h[(size_t)r * DF + n0 + nt * 16 + lr] = __float2half(acc[mt][nt][j]);
            }
        }
    }
}

// ---------------- Aggregation (R12-best: plain loads) ----------------
// One wave per node. Per 64-edge chunk: ONE coalesced csr load (clamped =
// dupe-safe under max), ids broadcast via __shfl, then uint4 gathers: 16 lanes
// x 16B per row -> 4 rows per VMEM instruction, 4 independent gathers per
// 16-edge step. Plain loads: L2 provides ~64% hit on repeated rows (nt hurt).

__global__ __launch_bounds__(256) void agg_kernel(const __half* __restrict__ hin,
        const int* __restrict__ off, const unsigned short* __restrict__ csr,
        float* __restrict__ out, _Float16* __restrict__ xf, int n, int split) {
    int wid = threadIdx.x >> 6;
    int lane = threadIdx.x & 63;
    int node = blockIdx.x * 4 + wid;
    if (node >= n) return;

    int q = lane >> 4;           // quarter: which of 4 edges in a 16-edge step
    int c = lane & 15;           // 16B column within 256B row

    int beg = off[node];
    int end = off[node + 1];

    unsigned m0 = 0xFC00FC00u, m1 = m0, m2 = m0, m3 = m0;

    if (beg < end) {
        int e1 = end - 1;
        int deg = end - beg;
        for (int base = 0; base < deg; base += 64) {
            int myid = csr[min(beg + base + lane, e1)];
            int lim = min(deg - base, 64);
            for (int t = 0; t < lim; t += 16) {
                int i0 = __shfl(myid, t + q);
                int i1 = __shfl(myid, t + q + 4);
                int i2 = __shfl(myid, t + q + 8);
                int i3 = __shfl(myid, t + q + 12);
                uint4 a = *(const uint4*)((const char*)hin + ((size_t)i0 << 8) + (c << 4));
                uint4 b = *(const uint4*)((const char*)hin + ((size_t)i1 << 8) + (c << 4));
                uint4 d = *(const uint4*)((const char*)hin + ((size_t)i2 << 8) + (c << 4));
                uint4 e = *(const uint4*)((const char*)hin + ((size_t)i3 << 8) + (c << 4));
                m0 = pkmax(m0, pkmax(pkmax(a.x, b.x), pkmax(d.x, e.x)));
                m1 = pkmax(m1, pkmax(pkmax(a.y, b.y), pkmax(d.y, e.y)));
                m2 = pkmax(m2, pkmax(pkmax(a.z, b.z), pkmax(d.z, e.z)));
                m3 = pkmax(m3, pkmax(pkmax(a.w, b.w), pkmax(d.w, e.w)));
            }
        }
        // reduce across quarters (lane i <-> i^16, i^32)
        m0 = pkmax(m0, (unsigned)__shfl_xor((int)m0, 16));
        m0 = pkmax(m0, (unsigned)__shfl_xor((int)m0, 32));
        m1 = pkmax(m1, (unsigned)__shfl_xor((int)m1, 16));
        m1 = pkmax(m1, (unsigned)__shfl_xor((int)m1, 32));
        m2 = pkmax(m2, (unsigned)__shfl_xor((int)m2, 16));
        m2 = pkmax(m2, (unsigned)__shfl_xor((int)m2, 32));
        m3 = pkmax(m3, (unsigned)__shfl_xor((int)m3, 16));
        m3 = pkmax(m3, (unsigned)__shfl_xor((int)m3, 32));
    }

    if (q != 0) return;

    float f[8];
    f[0] = h2f((unsigned short)(m0 & 0xFFFF)); f[1] = h2f((unsigned short)(m0 >> 16));
    f[2] = h2f((unsigned short)(m1 & 0xFFFF)); f[3] = h2f((unsigned short)(m1 >> 16));
    f[4] = h2f((unsigned short)(m2 & 0xFFFF)); f[5] = h2f((unsigned short)(m2 >> 16));
    f[6] = h2f((unsigned short)(m3 & 0xFFFF)); f[7] = h2f((unsigned short)(m3 >> 16));
    if (beg == end) {
#pragma unroll
        for (int j = 0; j < 8; ++j) f[j] = 0.0f;
    }

    if (split) {
        f16x8 v;
#pragma unroll
        for (int j = 0; j < 8; ++j) v[j] = (_Float16)silu(f[j]);
        *reinterpret_cast<f16x8*>(xf + (size_t)node * DF + c * 8) = v;
    } else {
        float4* o = (float4*)(out + (size_t)node * DF + c * 8);
        o[0] = make_float4(f[0], f[1], f[2], f[3]);
        o[1] = make_float4(f[4], f[5], f[6], f[7]);
    }
}

// ---------------- Launch ----------------

extern "C" void kernel_launch(void* const* d_in, const int* in_sizes, int n_in,
                              void* d_out, int out_size, void* d_ws, size_t ws_size,
                              hipStream_t stream) {
    const float* x  = (const float*)d_in[0];
    const int*   ei = (const int*)d_in[1];
    const float* Ws = (const float*)d_in[2];
    const float* bs = (const float*)d_in[3];
    float* out = (float*)d_out;

    int N = in_sizes[0] / DF;
    int E = in_sizes[1] / 2;
    const int* src = ei;
    const int* dst = ei + E;

    char* w = (char*)d_ws;
    auto carve = [&](size_t bytes) {
        char* p = w;
        w += (bytes + 255) & ~(size_t)255;
        return p;
    };
    int nb = (N + 255) / 256;
    int*            cnt  = (int*)carve((size_t)(N + 1) * sizeof(int));
    int*            off  = (int*)carve((size_t)(N + 1) * sizeof(int));
    int*            bsum = (int*)carve((size_t)nb * sizeof(int));
    unsigned short* rank = (unsigned short*)carve((size_t)E * sizeof(unsigned short));
    unsigned short* csr  = (unsigned short*)carve((size_t)E * sizeof(unsigned short));
    __half*         h    = (__half*)carve((size_t)N * DF * sizeof(__half));
    _Float16*       xf   = (_Float16*)carve((size_t)N * DF * sizeof(_Float16));
    _Float16*       whf  = (_Float16*)carve((size_t)NLAYERS * DF * DF * sizeof(_Float16));
    _Float16*       wlf  = (_Float16*)carve((size_t)NLAYERS * DF * DF * sizeof(_Float16));

    int nbE = (E + 255) / 256;
    int wt4 = NLAYERS * DF * DF / 4;
    int nbW = (wt4 + 255) / 256;
    int ggrid = (N + 63) / 64;
    int agrid = (N + 3) / 4;

    // ---- CSR build + W fp16-pair split ----
    zero_kernel<<<nb, 256, 0, stream>>>(cnt, N);
    prep_kernel<<<nbE + nbW, 256, 0, stream>>>(dst, cnt, rank, E, nbE, Ws, whf, wlf, wt4);
    partial_sum_kernel<<<nb, 256, 0, stream>>>(cnt, bsum, N);
    scan_scatter_kernel<<<nb, 256, 0, stream>>>(cnt, bsum, off, N, E, nb);

    // ---- CSR fill co-launched with layer-0 gemm ----
    fill_gemm0_kernel<<<nbE + ggrid, 256, 0, stream>>>(
        src, dst, off, rank, csr, E, nbE, x, whf, wlf, bs, h, N);

    // ---- layers 1..4: agg -> xf (SiLU, fp16), gemm -> h; final agg -> out ----
    for (int layer = 1; layer < NLAYERS; ++layer) {
        agg_kernel<<<agrid, 256, 0, stream>>>(h, off, csr, out, xf, N, 1);
        const _Float16* whl = whf + (size_t)layer * DF * DF;
        const _Float16* wll = wlf + (size_t)layer * DF * DF;
        const float* bl = bs + (size_t)layer * DF;
        gemm_f16_kernel<<<ggrid, 256, 0, stream>>>(xf, whl, wll, bl, h, N);
    }
    agg_kernel<<<agrid, 256, 0, stream>>>(h, off, csr, out, NULL, N, 0);
}